// Round 7
// baseline (810.650 us; speedup 1.0000x reference)
//
#include <hip/hip_runtime.h>
#include <hip/hip_bf16.h>
#include <math.h>

// ---------------------------------------------------------------------------
// MjCambrianOptics: depth-invariant PSF (f64 DFT-as-matmul, matching numpy's
// complex128 FFT promotion) + f32 255x255 SAME depthwise conv.
// Phase-critical bits replicate numpy EXACTLY:
//   * ki = fl32(2pi)/fl32(wl), f32 IEEE divide (np NEP-50 weak scalar == jax)
//   * mean(depth) = numpy BUFFERED reduce: d = a[0], then for each <=8192
//     chunk of a[1..]: d += pairwise_sum(chunk)   [nditer buffersize 8192]
//     pairwise_sum = numpy's 128-leaf / 8-accumulator recursion
//   * linspace grids: f64 (i*step + start), endpoint forced, cast to f32
//   * th = fl32(ki*s); ph = fl32(fl32(ki*d)*FXY); numpy op order, contract off
// ---------------------------------------------------------------------------

constexpr int M   = 255;
constexpr int NP  = M * M;        // 65025
constexpr int RESO = 160;

// ---------------- numpy buffered-reduce pairwise forest (compile-time) ------
constexpr int MAXN = 1100;
struct PWForest {
    int kind[MAXN];   // 0 leaf, 1 internal
    int off[MAXN], len[MAXN];
    int li[MAXN], ri[MAXN];
    int lvl[MAXN];
    int leafIdx[MAXN];
    int nNode, nLeaf, maxLvl;
    int roots[16], nRoots;
};
constexpr int pwf_build(PWForest& T, int o, int n) {
    if (n <= 128) {
        int id = T.nNode++;
        T.kind[id] = 0; T.off[id] = o; T.len[id] = n;
        T.lvl[id] = 0; T.leafIdx[id] = T.nLeaf++;
        return id;
    }
    int n2 = (n / 2) - ((n / 2) % 8);
    int a = pwf_build(T, o, n2);
    int b = pwf_build(T, o + n2, n - n2);
    int id = T.nNode++;
    T.kind[id] = 1; T.li[id] = a; T.ri[id] = b;
    int l = (T.lvl[a] > T.lvl[b] ? T.lvl[a] : T.lvl[b]) + 1;
    T.lvl[id] = l; if (l > T.maxLvl) T.maxLvl = l;
    return id;
}
constexpr PWForest pwf_make() {
    PWForest T{};
    int pos = 1, rem = NP - 1;            // reduce skips a[0] (seed)
    while (rem > 0) {
        int c = rem > 8192 ? 8192 : rem;  // nditer buffer = 8192 elements
        T.roots[T.nRoots++] = pwf_build(T, pos, c);
        pos += c; rem -= c;
    }
    return T;
}
constexpr PWForest PW = pwf_make();
static_assert(PW.nNode <= MAXN, "forest overflow");
static_assert(PW.maxLvl <= 16, "depth overflow");
static_assert(PW.nRoots == 8, "chunk count");

struct PWLeaves { int off[600]; int len[600]; int n; };
constexpr PWLeaves pw_leaves() {
    PWLeaves L{};
    for (int i = 0; i < PW.nNode; ++i)
        if (PW.kind[i] == 0) { L.off[L.n] = PW.off[i]; L.len[L.n] = PW.len[i]; L.n++; }
    return L;
}
constexpr PWLeaves PWL = pw_leaves();
static_assert(PWL.n <= 600, "leaf overflow");

// Leaf sums: numpy's exact 8-accumulator loop per leaf.
__global__ void k_leaf(const float* __restrict__ depth, float* __restrict__ leafVal) {
    int t = blockIdx.x * 256 + threadIdx.x;
    if (t >= PWL.n) return;
    const float* a = depth + PWL.off[t];
    int n = PWL.len[t];
    float r0 = a[0], r1 = a[1], r2 = a[2], r3 = a[3];
    float r4 = a[4], r5 = a[5], r6 = a[6], r7 = a[7];
    int lim = n - (n % 8);
    int i = 8;
    for (; i < lim; i += 8) {
        r0 += a[i + 0]; r1 += a[i + 1]; r2 += a[i + 2]; r3 += a[i + 3];
        r4 += a[i + 4]; r5 += a[i + 5]; r6 += a[i + 6]; r7 += a[i + 7];
    }
    float res = ((r0 + r1) + (r2 + r3)) + ((r4 + r5) + (r6 + r7));
    for (; i < n; ++i) res += a[i];
    leafVal[t] = res;
}

// Combine within chunks (numpy association), then sequential chunk chain.
__global__ void k_comb(const float* __restrict__ depth,
                       const float* __restrict__ leafVal, float* __restrict__ meanp) {
    __shared__ float val[MAXN];
    int tid = threadIdx.x;
    for (int id = tid; id < PW.nNode; id += 256)
        if (PW.kind[id] == 0) val[id] = leafVal[PW.leafIdx[id]];
    __syncthreads();
    for (int l = 1; l <= PW.maxLvl; ++l) {
        for (int id = tid; id < PW.nNode; id += 256)
            if (PW.kind[id] == 1 && PW.lvl[id] == l)
                val[id] = val[PW.li[id]] + val[PW.ri[id]];
        __syncthreads();
    }
    if (tid == 0) {
        float io1 = depth[0];                       // reduce seeds with a[0]
        for (int r = 0; r < PW.nRoots; ++r)
            io1 = io1 + val[PW.roots[r]];           // sequential chunk adds
        meanp[0] = io1 / 65025.0f;                  // f32 divide, np._mean
    }
}

// ---------------- DFT matrix W[n,k] = exp(-2*pi*i*n*k/255), f64 -------------
__global__ void k_W64(double2* __restrict__ W) {
    int idx = blockIdx.x * 256 + threadIdx.x;
    if (idx >= NP) return;
    int n = idx / M, k = idx % M;
    int m = (n * k) % M;
    double ang = -2.0 * 3.14159265358979323846 * (double)m / 255.0;
    W[idx] = make_double2(cos(ang), sin(ang));
}

// ---------------- u2 and H fields: numpy-complex64-faithful (f32) -----------
__global__ void k_u2H(const float* __restrict__ meanp,
                      float2* __restrict__ U2, float2* __restrict__ Hb,
                      double xstart, double xstep, double xstop,
                      double fstart, double fstep, double fstop,
                      float ap_f) {
#pragma clang fp contract(off)
    int idx = blockIdx.x * 256 + threadIdx.x;
    if (idx >= 3 * NP) return;
    int c = idx / NP, ij = idx % NP, i = ij / M, j = ij % M;
    const float wls[3] = {6.1e-07f, 5.3e-07f, 4.7e-07f};
    float wl = wls[c];
    float ki = ((float)6.283185307179586) / wl;   // fl32(2pi)/wl, f32 IEEE div
    float d  = meanp[0];
    float d2 = d * d;

    float x  = (i == 254) ? (float)xstop : (float)((double)i * xstep + xstart);
    float y  = (j == 254) ? (float)xstop : (float)((double)j * xstep + xstart);
    float fx = (i == 254) ? (float)fstop : (float)((double)i * fstep + fstart);
    float fy = (j == 254) ? (float)fstop : (float)((double)j * fstep + fstart);

    float xx = x * x, yy = y * y;
    float X1Y1 = xx + yy;

    float s  = sqrtf(X1Y1 + d2);
    float th = ki * s;
    float A  = (sqrtf(X1Y1) / ap_f <= 1.0f) ? 1.0f : 0.0f;
    float2 u2v;
    if (A != 0.0f) u2v = make_float2((float)cos((double)th), (float)sin((double)th));
    else           u2v = make_float2(0.0f, 0.0f);

    float a = wl * fx, b = wl * fy;
    float arg = (1.0f - a * a) - b * b;
    float FXY = sqrtf(fmaxf(arg, 0.0f));
    float Hv  = (sqrtf(fx * fx + fy * fy) < (1.0f / wl)) ? 1.0f : 0.0f;
    float kd  = ki * d;
    float ph  = kd * FXY;
    float cph = (float)cos((double)ph), sph = (float)sin((double)ph);
    float2 hv = make_float2(Hv * cph, Hv * sph);

    U2[idx] = u2v;
    Hb[idx] = hv;
}

// ---------------- batched f64 complex GEMM: C = scale * opA(A)*opB(B) -------
__global__ __launch_bounds__(256)
void k_cgemm64(const double2* __restrict__ A, int aBatch,
               const float2* __restrict__ Bf,
               const double2* __restrict__ Bd, int bBatch,
               double2* __restrict__ C,
               int conjA, int conjB, double scale) {
    __shared__ double2 As[16][16];
    __shared__ double2 Bs[16][16];
    int c = blockIdx.z;
    int i = blockIdx.y * 16 + threadIdx.y;
    int j = blockIdx.x * 16 + threadIdx.x;
    const double2* Ab = A + (size_t)c * aBatch;
    double accx = 0.0, accy = 0.0;
    for (int kt = 0; kt < 16; ++kt) {
        int ka = kt * 16 + threadIdx.x;
        int kb = kt * 16 + threadIdx.y;
        double2 av = (i < M && ka < M) ? Ab[i * M + ka] : make_double2(0.0, 0.0);
        double2 bv;
        if (kb < M && j < M) {
            if (Bf) {
                float2 t = Bf[(size_t)c * bBatch + kb * M + j];
                bv = make_double2((double)t.x, (double)t.y);
            } else {
                bv = Bd[(size_t)c * bBatch + kb * M + j];
            }
        } else bv = make_double2(0.0, 0.0);
        if (conjA) av.y = -av.y;
        if (conjB) bv.y = -bv.y;
        As[threadIdx.y][threadIdx.x] = av;
        Bs[threadIdx.y][threadIdx.x] = bv;
        __syncthreads();
#pragma unroll
        for (int kk = 0; kk < 16; ++kk) {
            double2 a = As[threadIdx.y][kk];
            double2 b = Bs[kk][threadIdx.x];
            accx = fma(a.x, b.x, fma(-a.y, b.y, accx));
            accy = fma(a.x, b.y, fma(a.y, b.x, accy));
        }
        __syncthreads();
    }
    if (i < M && j < M)
        C[(size_t)c * NP + i * M + j] = make_double2(accx * scale, accy * scale);
}

// ---------------- elementwise P = FH .* FU (f64) ----------------
__global__ void k_pmul64(const double2* __restrict__ FH, const double2* __restrict__ FU,
                         double2* __restrict__ P) {
    int idx = blockIdx.x * 256 + threadIdx.x;
    if (idx >= 3 * NP) return;
    double2 a = FH[idx], b = FU[idx];
    P[idx] = make_double2(a.x * b.x - a.y * b.y, a.x * b.y + a.y * b.x);
}

// ---------------- S = sum u3^2 (complex, f64) ----------------
__global__ void k_sred64(const double2* __restrict__ U3, double2* __restrict__ spart) {
    __shared__ double sx[256], sy[256];
    int t = threadIdx.x;
    double ax = 0.0, ay = 0.0;
    for (int i = blockIdx.x * 256 + t; i < 3 * NP; i += 64 * 256) {
        double2 z = U3[i];
        ax += z.x * z.x - z.y * z.y;
        ay += 2.0 * z.x * z.y;
    }
    sx[t] = ax; sy[t] = ay;
    __syncthreads();
    for (int w = 128; w > 0; w >>= 1) {
        if (t < w) { sx[t] += sx[t + w]; sy[t] += sy[t + w]; }
        __syncthreads();
    }
    if (t == 0) spart[blockIdx.x] = make_double2(sx[0], sy[0]);
}

__global__ void k_scomb64(const double2* __restrict__ spart, double2* __restrict__ Sp) {
    if (threadIdx.x != 0 || blockIdx.x != 0) return;
    double rx = 0.0, ry = 0.0;
    for (int i = 0; i < 64; ++i) { rx += spart[i].x; ry += spart[i].y; }
    Sp[0] = make_double2(rx + 1e-7, ry);
}

// ---------------- psf = Re(u3^2 / denom), f64 -> f32 ----------------
__global__ void k_psf64(const double2* __restrict__ U3, const double2* __restrict__ Sp,
                        float* __restrict__ PSF) {
    int idx = blockIdx.x * 256 + threadIdx.x;
    if (idx >= 3 * NP) return;
    double2 den = Sp[0];
    double inv = 1.0 / (den.x * den.x + den.y * den.y);
    double2 z = U3[idx];
    double zr = z.x * z.x - z.y * z.y;
    double zi = 2.0 * z.x * z.y;
    PSF[idx] = (float)((zr * den.x + zi * den.y) * inv);
}

// ---------------- image HWC -> planar CHW ----------------
__global__ void k_transpose(const float* __restrict__ img, float* __restrict__ imgP) {
    int idx = blockIdx.x * 256 + threadIdx.x;
    if (idx >= 3 * NP) return;
    int c = idx / NP, ij = idx % NP;
    imgP[idx] = img[ij * 3 + c];
}

// ---------------- split-K tiled direct conv (f32) ----------------
__global__ __launch_bounds__(128)
void k_conv(const float* __restrict__ imgP, const float* __restrict__ PSF,
            float* __restrict__ PART) {
    constexpr int BI = 64, BJ = 32, DI = 16, DJ = 32;
    constexpr int ROWS = BI + DI - 1;   // 79
    constexpr int COLS = 64;
    __shared__ __align__(16) float simg[ROWS * COLS];
    __shared__ __align__(16) float spsf[DI * DJ];

    int tid = threadIdx.x;
    int tj = tid & 7, ti = tid >> 3;
    int j0 = blockIdx.x * BJ;
    int i0 = blockIdx.y * BI;
    int cz = blockIdx.z;
    int c = cz >> 4, kz = cz & 15;
    int d0 = kz * DI;
    int rowBase = i0 + d0 - 80;
    const float* ip = imgP + (size_t)c * NP;
    const float* pp = PSF  + (size_t)c * NP;

    float acc[4][4];
#pragma unroll
    for (int r = 0; r < 4; ++r)
#pragma unroll
        for (int q = 0; q < 4; ++q) acc[r][q] = 0.0f;

    for (int djt = 0; djt < 8; ++djt) {
        int dj0 = djt * DJ;
        int colBase = j0 + dj0 - 80;
        __syncthreads();
        for (int idx = tid; idx < ROWS * COLS; idx += 128) {
            int rr = idx >> 6, cc = idx & 63;
            int aa = rowBase + rr, bb = colBase + cc;
            float v = 0.0f;
            if (aa >= 0 && aa < M && bb >= 0 && bb < M && cc < 63) v = ip[aa * M + bb];
            simg[idx] = v;
        }
        for (int idx = tid; idx < DI * DJ; idx += 128) {
            int r = idx >> 5, q = idx & 31;
            int di = d0 + r, dj = dj0 + q;
            spsf[idx] = (di < M && dj < M) ? pp[di * M + dj] : 0.0f;
        }
        __syncthreads();

        for (int dik = 0; dik < DI; ++dik) {
            const float* prow  = &spsf[dik * DJ];
            const float* irow0 = &simg[(ti * 4 + dik) * COLS + tj * 4];
#pragma unroll
            for (int djq = 0; djq < DJ; djq += 4) {
                float4 p = *(const float4*)(prow + djq);
#pragma unroll
                for (int r = 0; r < 4; ++r) {
                    const float* rp = irow0 + r * COLS + djq;
                    float4 wA = *(const float4*)(rp);
                    float4 wB = *(const float4*)(rp + 4);
                    acc[r][0] += wA.x * p.x + wA.y * p.y + wA.z * p.z + wA.w * p.w;
                    acc[r][1] += wA.y * p.x + wA.z * p.y + wA.w * p.z + wB.x * p.w;
                    acc[r][2] += wA.z * p.x + wA.w * p.y + wB.x * p.z + wB.y * p.w;
                    acc[r][3] += wA.w * p.x + wB.x * p.y + wB.y * p.z + wB.z * p.w;
                }
            }
        }
    }

    float* op = PART + (size_t)(c * 16 + kz) * (RESO * RESO);
#pragma unroll
    for (int r = 0; r < 4; ++r) {
        int i = i0 + ti * 4 + r;
        if (i < RESO) {
#pragma unroll
            for (int q = 0; q < 4; ++q) {
                int j = j0 + tj * 4 + q;
                op[i * RESO + j] = acc[r][q];
            }
        }
    }
}

// ---------------- reduce partials + clip + layout (i,j,c) ----------------
__global__ void k_out(const float* __restrict__ PART, float* __restrict__ out) {
    int idx = blockIdx.x * 256 + threadIdx.x;
    if (idx >= 3 * RESO * RESO) return;
    int c = idx / (RESO * RESO), ij = idx % (RESO * RESO);
    float s = 0.0f;
    for (int kz = 0; kz < 16; ++kz)
        s += PART[(size_t)(c * 16 + kz) * (RESO * RESO) + ij];
    s = fminf(fmaxf(s, 0.0f), 1.0f);
    int i = ij / RESO, j = ij % RESO;
    out[(i * RESO + j) * 3 + c] = s;
}

// ---------------------------------------------------------------------------
extern "C" void kernel_launch(void* const* d_in, const int* in_sizes, int n_in,
                              void* d_out, int out_size, void* d_ws, size_t ws_size,
                              hipStream_t stream) {
    const float* image = (const float*)d_in[0];   // (255,255,3)
    const float* depth = (const float*)d_in[1];   // (255,255)
    float* out = (float*)d_out;                   // (160,160,3)

    // workspace carve (256B aligned), ~23 MB total
    char* p = (char*)d_ws;
    auto alloc = [&](size_t bytes) { void* r = (void*)p; p += (bytes + 255) & ~(size_t)255; return r; };
    float*   meanp   = (float*)alloc(4);
    float*   leafVal = (float*)alloc(600 * 4);
    double2* Wd    = (double2*)alloc((size_t)NP * 16);
    float2*  U2    = (float2*)alloc((size_t)3 * NP * 8);
    float2*  Hb    = (float2*)alloc((size_t)3 * NP * 8);
    double2* Td    = (double2*)alloc((size_t)3 * NP * 16);
    double2* Ed    = (double2*)alloc((size_t)3 * NP * 16);
    double2* Fd    = (double2*)alloc((size_t)3 * NP * 16);
    double2* U3d   = (double2*)alloc((size_t)3 * NP * 16);
    double2* spart = (double2*)alloc(64 * 16);
    double2* Sp    = (double2*)alloc(16);
    float*   PSF   = (float*)alloc((size_t)3 * NP * 4);
    float*   IMGP  = (float*)alloc((size_t)3 * NP * 4);
    float*   PART  = (float*)alloc((size_t)48 * RESO * RESO * 4);

    // exact python-f64 scalar path
    double dx = 0.002 / 255.0;
    double Lx = dx * 255.0;
    double ap = (Lx / 2.0) * 0.1 + 1e-7;
    float ap_f = (float)ap;

    double xstart = -(Lx / 2.0);
    double xstop  =  Lx / 2.0;
    double xstep  = (xstop - xstart) / 254.0;
    double fstart = -1.0 / (2.0 * dx);
    double fstop  =  1.0 / (2.0 * dx);
    double fstep  = (fstop - fstart) / 254.0;

    int g3 = (3 * NP + 255) / 256;   // 763
    int g1 = (NP + 255) / 256;       // 254

    k_transpose<<<g3, 256, 0, stream>>>(image, IMGP);
    k_leaf<<<(PWL.n + 255) / 256, 256, 0, stream>>>(depth, leafVal);
    k_comb<<<1, 256, 0, stream>>>(depth, leafVal, meanp);
    k_W64<<<g1, 256, 0, stream>>>(Wd);
    k_u2H<<<g3, 256, 0, stream>>>(meanp, U2, Hb,
                                  xstart, xstep, xstop,
                                  fstart, fstep, fstop, ap_f);

    dim3 gg(16, 16, 3), bb(16, 16);
    // FU = (W*U2)*W   -> Ed
    k_cgemm64<<<gg, bb, 0, stream>>>(Wd, 0, U2, nullptr, NP, Td, 0, 0, 1.0);
    k_cgemm64<<<gg, bb, 0, stream>>>(Td, NP, nullptr, Wd, 0, Ed, 0, 0, 1.0);
    // FH = (W*H)*W    -> Fd
    k_cgemm64<<<gg, bb, 0, stream>>>(Wd, 0, Hb, nullptr, NP, Td, 0, 0, 1.0);
    k_cgemm64<<<gg, bb, 0, stream>>>(Td, NP, nullptr, Wd, 0, Fd, 0, 0, 1.0);
    // P = FH .* FU    -> Td
    k_pmul64<<<g3, 256, 0, stream>>>(Fd, Ed, Td);
    // u3 = (1/255^2) * conj(W)*P*conj(W)  -> U3d
    k_cgemm64<<<gg, bb, 0, stream>>>(Wd, 0, nullptr, Td, NP, Ed, 1, 0, 1.0 / 255.0);
    k_cgemm64<<<gg, bb, 0, stream>>>(Ed, NP, nullptr, Wd, 0, U3d, 0, 1, 1.0 / 255.0);

    k_sred64<<<64, 256, 0, stream>>>(U3d, spart);
    k_scomb64<<<1, 64, 0, stream>>>(spart, Sp);
    k_psf64<<<g3, 256, 0, stream>>>(U3d, Sp, PSF);

    dim3 cg(5, 3, 48);
    k_conv<<<cg, 128, 0, stream>>>(IMGP, PSF, PART);
    k_out<<<300, 256, 0, stream>>>(PART, out);
}